// Round 9
// baseline (195.585 us; speedup 1.0000x reference)
//
#include <hip/hip_runtime.h>
#include <hip/hip_bf16.h>

typedef unsigned short ushortT;
typedef unsigned int uintT;
typedef __attribute__((ext_vector_type(8))) short short8;
typedef __attribute__((ext_vector_type(4))) float f32x4;

#define BATCH   2048
#define NELEC   64
#define BN_EPS  1e-5f

// ws float-offset layout (stats/coeff region)
#define OFF_AMEAN  4096
#define OFF_SS1    4160                 // scale1[64], shift1[64]
#define OFF_SS2    4288                 // scale2[128], shift2[128]
#define OFF_PS1    4544                 // [64 slots][64]
#define OFF_PQ1    8640
#define OFF_PS2    12736                // [64 slots][128]
#define OFF_PQ2    20928                // ends 29120
// ushort region U = (ushortT*)(ws + 29120):
#define UOFF_A     0                    // A72 hi[64][72], lo[64][72]
#define UOFF_W1T   9216                 // W1t hi[64][72], lo[64][72]   (W1t[o][k])
#define UOFF_W2T   18432                // W2t hi[128][72], lo[128][72] (W2t[o][k])
#define UOFF_H1    36864                // h1[b][n][o]   bf16  2048*64*64
#define UOFF_H2    8425472              // h2[b][n][o2]  bf16  2048*64*128
#define UOFF_T1    25202688             // T1[b][o][n]   bf16  2048*64*64
#define UOFF_T2    25202688             // T2[b][o2][n]  bf16  2048*128*64 (reuses T1)

#define MFMA(a, b, c) __builtin_amdgcn_mfma_f32_16x16x32_bf16(a, b, c, 0, 0, 0)

__device__ inline float bf2f(ushortT u) { return __uint_as_float(((uintT)u) << 16); }
__device__ inline ushortT f2bf(float f) {
  uintT u = __float_as_uint(f);
  u = (u + 0x7FFFu + ((u >> 16) & 1u)) >> 16;
  return (ushortT)u;
}
__device__ inline void split2(float f, ushortT& hi, ushortT& lo) {
  hi = f2bf(f);
  lo = f2bf(f - bf2f(hi));
}
// truncation split: hi = trunc bits (exact residual), lo = rounded residual
__device__ inline void splitT8(const float* f, short8& hi, short8& lo) {
  #pragma unroll
  for (int e = 0; e < 8; ++e) {
    uintT u = __float_as_uint(f[e]);
    float fh = __uint_as_float(u & 0xFFFF0000u);
    hi[e] = (short)(u >> 16);
    lo[e] = (short)f2bf(f[e] - fh);
  }
}
__device__ inline uint2 pack4(f32x4 v) {
  uint2 pk;
  pk.x = (uintT)f2bf(v[0]) | ((uintT)f2bf(v[1]) << 16);
  pk.y = (uintT)f2bf(v[2]) | ((uintT)f2bf(v[3]) << 16);
  return pk;
}

// ---------------- prep: A72/W1T/W2T (stride-72 padded, hi/lo), amean ----------------
__global__ __launch_bounds__(256) void prep_kernel(const int* __restrict__ src,
    const int* __restrict__ dst, int E,
    const float* __restrict__ W1, const float* __restrict__ W2,
    float* __restrict__ ws) {
  __shared__ float degS[NELEC];
  __shared__ float As[NELEC * NELEC];
  int t = threadIdx.x;
  if (t < NELEC) degS[t] = 1.0f;               // self-loop
  for (int i = t; i < NELEC * NELEC; i += 256) As[i] = 0.0f;
  __syncthreads();
  for (int e = t; e < E; e += 256) atomicAdd(&degS[dst[e]], 1.0f);
  __syncthreads();
  for (int e = t; e < E; e += 256) {
    float en = rsqrtf(degS[src[e]]) * rsqrtf(degS[dst[e]]);
    atomicAdd(&As[dst[e] * NELEC + src[e]], en);
  }
  __syncthreads();
  if (t < NELEC) As[t * NELEC + t] += 1.0f / degS[t];
  __syncthreads();
  ushortT* U = (ushortT*)(ws + 29120);
  ushortT* a72 = U + UOFF_A;
  for (int i = t; i < 4096; i += 256) {
    int row = i >> 6, k = i & 63;
    ushortT hi, lo; split2(As[i], hi, lo);
    a72[row * 72 + k] = hi; a72[4608 + row * 72 + k] = lo;
  }
  if (t < NELEC) {
    float s = 0.0f;
    for (int n = 0; n < NELEC; ++n) s += As[n * NELEC + t];
    ws[OFF_AMEAN + t] = s * (1.0f / NELEC);
  }
  ushortT* w1t = U + UOFF_W1T;
  for (int i = t; i < 4096; i += 256) {
    int o = i >> 6, k = i & 63;
    ushortT hi, lo; split2(W1[k * 64 + o], hi, lo);
    w1t[o * 72 + k] = hi; w1t[4608 + o * 72 + k] = lo;
  }
  ushortT* w2t = U + UOFF_W2T;
  for (int i = t; i < 8192; i += 256) {
    int o = i >> 6, k = i & 63;
    ushortT hi, lo; split2(W2[k * 128 + o], hi, lo);
    w2t[o * 72 + k] = hi; w2t[9216 + o * 72 + k] = lo;
  }
}

// ---------------- wgemm1: T1[b][o][n] = X[b] @ W1  (unit = item × n-half) ----------------
__global__ __launch_bounds__(256, 4) void wgemm1_kernel(const float* __restrict__ x,
    float* __restrict__ ws) {
  __shared__ ushortT Wl[9216];
  const int t = threadIdx.x;
  ushortT* U = (ushortT*)(ws + 29120);
  for (int i = t; i < 1152; i += 256)
    ((uint4*)Wl)[i] = ((const uint4*)(U + UOFF_W1T))[i];
  const int w = t >> 6, lane = t & 63, c = lane & 15, g = lane >> 4;
  const int wv = blockIdx.x * 4 + w;
  const int b = wv >> 1, nh = wv & 1;
  // X fragments: rows n = (nh*2+nq)*16+c, trunc hi/lo split
  short8 Xh[2][2], Xl[2][2];
  #pragma unroll
  for (int nq = 0; nq < 2; ++nq) {
    #pragma unroll
    for (int ks = 0; ks < 2; ++ks) {
      const float* p = x + (size_t)b * 4096 + ((nh * 2 + nq) * 16 + c) * 64 + ks * 32 + g * 8;
      float4 fa = *(const float4*)p, fb = *(const float4*)(p + 4);
      float f[8] = {fa.x, fa.y, fa.z, fa.w, fb.x, fb.y, fb.z, fb.w};
      splitT8(f, Xh[nq][ks], Xl[nq][ks]);
    }
  }
  __syncthreads();
  f32x4 acc[2][4];
  #pragma unroll
  for (int i = 0; i < 2; ++i)
    #pragma unroll
    for (int j = 0; j < 4; ++j) acc[i][j] = (f32x4){0.f, 0.f, 0.f, 0.f};
  #pragma unroll
  for (int ot = 0; ot < 4; ++ot) {
    #pragma unroll
    for (int ks = 0; ks < 2; ++ks) {
      short8 bh = *(const short8*)&Wl[(ot * 16 + c) * 72 + ks * 32 + g * 8];
      short8 bl = *(const short8*)&Wl[4608 + (ot * 16 + c) * 72 + ks * 32 + g * 8];
      #pragma unroll
      for (int nq = 0; nq < 2; ++nq) {
        acc[nq][ot] = MFMA(Xh[nq][ks], bh, acc[nq][ot]);
        acc[nq][ot] = MFMA(Xh[nq][ks], bl, acc[nq][ot]);
        acc[nq][ot] = MFMA(Xl[nq][ks], bh, acc[nq][ot]);
      }
    }
  }
  ushortT* t1 = U + UOFF_T1 + (size_t)b * 4096;
  #pragma unroll
  for (int ot = 0; ot < 4; ++ot)
    #pragma unroll
    for (int nq = 0; nq < 2; ++nq)
      *(uint2*)&t1[(ot * 16 + c) * 64 + (nh * 2 + nq) * 16 + 4 * g] = pack4(acc[nq][ot]);
}

// ---------------- agemm1: h1[b][n'][o] = A @ T1[b] + b1  (unit = item × o-half, PURE) ----------------
__global__ __launch_bounds__(256, 4) void agemm1_kernel(const float* __restrict__ b1,
    float* __restrict__ ws) {
  const int t = threadIdx.x, w = t >> 6, lane = t & 63, c = lane & 15, g = lane >> 4;
  const int wv = blockIdx.x * 4 + w;
  const int b = wv >> 1, oh = wv & 1;
  ushortT* U = (ushortT*)(ws + 29120);
  const ushortT* t1 = U + UOFF_T1 + (size_t)b * 4096;
  short8 tf[2][2];
  #pragma unroll
  for (int rt = 0; rt < 2; ++rt)
    #pragma unroll
    for (int ks = 0; ks < 2; ++ks)
      tf[rt][ks] = *(const short8*)(t1 + (oh * 32 + rt * 16 + c) * 64 + ks * 32 + g * 8);
  float4 bv[2];
  #pragma unroll
  for (int rt = 0; rt < 2; ++rt)
    bv[rt] = *(const float4*)(b1 + oh * 32 + rt * 16 + 4 * g);
  ushortT* h1 = U + UOFF_H1 + (size_t)b * 4096;
  #pragma unroll
  for (int sp = 0; sp < 4; ++sp) {
    short8 Bh[2], Bl[2];
    #pragma unroll
    for (int ks = 0; ks < 2; ++ks) {
      Bh[ks] = *(const short8*)(U + UOFF_A + (sp * 16 + c) * 72 + ks * 32 + g * 8);
      Bl[ks] = *(const short8*)(U + UOFF_A + 4608 + (sp * 16 + c) * 72 + ks * 32 + g * 8);
    }
    f32x4 acc[2] = {{0.f,0.f,0.f,0.f},{0.f,0.f,0.f,0.f}};
    #pragma unroll
    for (int ks = 0; ks < 2; ++ks)
      #pragma unroll
      for (int rt = 0; rt < 2; ++rt) {
        acc[rt] = MFMA(tf[rt][ks], Bh[ks], acc[rt]);
        acc[rt] = MFMA(tf[rt][ks], Bl[ks], acc[rt]);
      }
    #pragma unroll
    for (int rt = 0; rt < 2; ++rt) {
      acc[rt][0] += bv[rt].x; acc[rt][1] += bv[rt].y;
      acc[rt][2] += bv[rt].z; acc[rt][3] += bv[rt].w;
      *(uint2*)&h1[(sp * 16 + c) * 64 + oh * 32 + rt * 16 + 4 * g] = pack4(acc[rt]);
    }
  }
}

// ---------------- stats1: BN partial sums over h1 (bf16), no shuffles ----------------
__global__ __launch_bounds__(256, 4) void stats1_kernel(float* __restrict__ ws) {
  __shared__ float P[32 * 128];
  const int t = threadIdx.x;
  const int rg = t >> 3, oct = t & 7;
  const ushortT* h1 = (const ushortT*)(ws + 29120) + UOFF_H1;
  float S[8] = {}, Q[8] = {};
  const int r0 = blockIdx.x * 512 + rg * 16;
  for (int i = 0; i < 16; ++i) {
    short8 v = *(const short8*)(h1 + (size_t)(r0 + i) * 64 + oct * 8);
    #pragma unroll
    for (int e = 0; e < 8; ++e) {
      float f = bf2f((ushortT)v[e]);
      S[e] += f; Q[e] += f * f;
    }
  }
  #pragma unroll
  for (int e = 0; e < 8; ++e) {
    P[rg * 128 + oct * 8 + e] = S[e];
    P[rg * 128 + 64 + oct * 8 + e] = Q[e];
  }
  __syncthreads();
  if (t < 128) {
    float a = 0.f;
    #pragma unroll
    for (int r = 0; r < 32; ++r) a += P[r * 128 + t];
    const int slot = blockIdx.x & 63;
    if (t < 64) atomicAdd(&ws[OFF_PS1 + slot * 64 + t], a);
    else        atomicAdd(&ws[OFF_PQ1 + slot * 64 + (t - 64)], a);
  }
}

// ---------------- BN finalize ----------------
__global__ void reduce1_kernel(const float* __restrict__ g1, const float* __restrict__ be1,
                               float* __restrict__ ws) {
  int t = threadIdx.x;
  if (t < 64) {
    float S = 0.0f, Q = 0.0f;
    for (int s = 0; s < 64; ++s) { S += ws[OFF_PS1 + s * 64 + t]; Q += ws[OFF_PQ1 + s * 64 + t]; }
    const float inv = 1.0f / (float)(BATCH * NELEC);
    float m = S * inv;
    float v = fmaxf(Q * inv - m * m, 0.0f);
    float sc = g1[t] * rsqrtf(v + BN_EPS);
    ws[OFF_SS1 + t] = sc;
    ws[OFF_SS1 + 64 + t] = fmaf(-m, sc, be1[t]);
  }
}

__global__ void reduce2_kernel(const float* __restrict__ g2, const float* __restrict__ be2,
                               float* __restrict__ ws) {
  int t = threadIdx.x;
  if (t < 128) {
    float S = 0.0f, Q = 0.0f;
    for (int s = 0; s < 64; ++s) { S += ws[OFF_PS2 + s * 128 + t]; Q += ws[OFF_PQ2 + s * 128 + t]; }
    const float inv = 1.0f / (float)(BATCH * NELEC);
    float m = S * inv;
    float v = fmaxf(Q * inv - m * m, 0.0f);
    float sc = g2[t] * rsqrtf(v + BN_EPS);
    ws[OFF_SS2 + t] = sc;
    ws[OFF_SS2 + 128 + t] = fmaf(-m, sc, be2[t]);
  }
}

// ---------------- wgemm2: T2[b][o2][n'] = relu(bn1(h1[b])) @ W2  (unit = item × n'-half) ----------------
__global__ __launch_bounds__(256, 3) void wgemm2_kernel(float* __restrict__ ws) {
  __shared__ ushortT Wl[18432];
  const int t = threadIdx.x;
  ushortT* U = (ushortT*)(ws + 29120);
  for (int i = t; i < 2304; i += 256)
    ((uint4*)Wl)[i] = ((const uint4*)(U + UOFF_W2T))[i];
  const int w = t >> 6, lane = t & 63, c = lane & 15, g = lane >> 4;
  const int wv = blockIdx.x * 4 + w;
  const int b = wv >> 1, nh = wv & 1;
  // BN coefficients for this lane's k-slots
  float s8[2][8], t8[2][8];
  #pragma unroll
  for (int ks = 0; ks < 2; ++ks) {
    const float* sp_ = ws + OFF_SS1 + ks * 32 + g * 8;
    const float* tp_ = ws + OFF_SS1 + 64 + ks * 32 + g * 8;
    float4 sa = *(const float4*)sp_, sb = *(const float4*)(sp_ + 4);
    float4 ta = *(const float4*)tp_, tb = *(const float4*)(tp_ + 4);
    s8[ks][0]=sa.x; s8[ks][1]=sa.y; s8[ks][2]=sa.z; s8[ks][3]=sa.w;
    s8[ks][4]=sb.x; s8[ks][5]=sb.y; s8[ks][6]=sb.z; s8[ks][7]=sb.w;
    t8[ks][0]=ta.x; t8[ks][1]=ta.y; t8[ks][2]=ta.z; t8[ks][3]=ta.w;
    t8[ks][4]=tb.x; t8[ks][5]=tb.y; t8[ks][6]=tb.z; t8[ks][7]=tb.w;
  }
  const ushortT* h1 = U + UOFF_H1 + (size_t)b * 4096;
  short8 Yh[2][2], Yl[2][2];
  #pragma unroll
  for (int nq = 0; nq < 2; ++nq) {
    #pragma unroll
    for (int ks = 0; ks < 2; ++ks) {
      short8 hv = *(const short8*)(h1 + ((nh * 2 + nq) * 16 + c) * 64 + ks * 32 + g * 8);
      float f[8];
      #pragma unroll
      for (int e = 0; e < 8; ++e)
        f[e] = fmaxf(fmaf(bf2f((ushortT)hv[e]), s8[ks][e], t8[ks][e]), 0.0f);
      splitT8(f, Yh[nq][ks], Yl[nq][ks]);
    }
  }
  __syncthreads();
  f32x4 acc[2][8];
  #pragma unroll
  for (int i = 0; i < 2; ++i)
    #pragma unroll
    for (int j = 0; j < 8; ++j) acc[i][j] = (f32x4){0.f, 0.f, 0.f, 0.f};
  #pragma unroll
  for (int ot = 0; ot < 8; ++ot) {
    #pragma unroll
    for (int ks = 0; ks < 2; ++ks) {
      short8 bh = *(const short8*)&Wl[(ot * 16 + c) * 72 + ks * 32 + g * 8];
      short8 bl = *(const short8*)&Wl[9216 + (ot * 16 + c) * 72 + ks * 32 + g * 8];
      #pragma unroll
      for (int nq = 0; nq < 2; ++nq) {
        acc[nq][ot] = MFMA(Yh[nq][ks], bh, acc[nq][ot]);
        acc[nq][ot] = MFMA(Yh[nq][ks], bl, acc[nq][ot]);
        acc[nq][ot] = MFMA(Yl[nq][ks], bh, acc[nq][ot]);
      }
    }
  }
  ushortT* t2 = U + UOFF_T2 + (size_t)b * 8192;
  #pragma unroll
  for (int ot = 0; ot < 8; ++ot)
    #pragma unroll
    for (int nq = 0; nq < 2; ++nq)
      *(uint2*)&t2[(ot * 16 + c) * 64 + (nh * 2 + nq) * 16 + 4 * g] = pack4(acc[nq][ot]);
}

// ---------------- agemm2: h2[b][n'][o2] = A @ T2[b] + b2  (unit = item × o2-half, PURE) ----------------
__global__ __launch_bounds__(256, 4) void agemm2_kernel(const float* __restrict__ b2,
    float* __restrict__ ws) {
  const int t = threadIdx.x, w = t >> 6, lane = t & 63, c = lane & 15, g = lane >> 4;
  const int wv = blockIdx.x * 4 + w;
  const int b = wv >> 1, oh = wv & 1;
  ushortT* U = (ushortT*)(ws + 29120);
  const ushortT* t2 = U + UOFF_T2 + (size_t)b * 8192;
  short8 tf[4][2];
  #pragma unroll
  for (int rt = 0; rt < 4; ++rt)
    #pragma unroll
    for (int ks = 0; ks < 2; ++ks)
      tf[rt][ks] = *(const short8*)(t2 + (oh * 64 + rt * 16 + c) * 64 + ks * 32 + g * 8);
  float4 bv[4];
  #pragma unroll
  for (int rt = 0; rt < 4; ++rt)
    bv[rt] = *(const float4*)(b2 + oh * 64 + rt * 16 + 4 * g);
  ushortT* h2 = U + UOFF_H2 + (size_t)b * 8192;
  #pragma unroll
  for (int sp = 0; sp < 4; ++sp) {
    short8 Bh[2], Bl[2];
    #pragma unroll
    for (int ks = 0; ks < 2; ++ks) {
      Bh[ks] = *(const short8*)(U + UOFF_A + (sp * 16 + c) * 72 + ks * 32 + g * 8);
      Bl[ks] = *(const short8*)(U + UOFF_A + 4608 + (sp * 16 + c) * 72 + ks * 32 + g * 8);
    }
    f32x4 acc[4];
    #pragma unroll
    for (int rt = 0; rt < 4; ++rt) acc[rt] = (f32x4){0.f, 0.f, 0.f, 0.f};
    #pragma unroll
    for (int ks = 0; ks < 2; ++ks)
      #pragma unroll
      for (int rt = 0; rt < 4; ++rt) {
        acc[rt] = MFMA(tf[rt][ks], Bh[ks], acc[rt]);
        acc[rt] = MFMA(tf[rt][ks], Bl[ks], acc[rt]);
      }
    #pragma unroll
    for (int rt = 0; rt < 4; ++rt) {
      acc[rt][0] += bv[rt].x; acc[rt][1] += bv[rt].y;
      acc[rt][2] += bv[rt].z; acc[rt][3] += bv[rt].w;
      *(uint2*)&h2[(sp * 16 + c) * 128 + oh * 64 + rt * 16 + 4 * g] = pack4(acc[rt]);
    }
  }
}

// ---------------- stats2: BN partial sums over h2 (bf16) ----------------
__global__ __launch_bounds__(256, 4) void stats2_kernel(float* __restrict__ ws) {
  __shared__ float P[16 * 256];
  const int t = threadIdx.x;
  const int rg = t >> 4, oct = t & 15;
  const ushortT* h2 = (const ushortT*)(ws + 29120) + UOFF_H2;
  float S[8] = {}, Q[8] = {};
  const int r0 = blockIdx.x * 512 + rg * 32;
  for (int i = 0; i < 32; ++i) {
    short8 v = *(const short8*)(h2 + (size_t)(r0 + i) * 128 + oct * 8);
    #pragma unroll
    for (int e = 0; e < 8; ++e) {
      float f = bf2f((ushortT)v[e]);
      S[e] += f; Q[e] += f * f;
    }
  }
  #pragma unroll
  for (int e = 0; e < 8; ++e) {
    P[rg * 256 + oct * 8 + e] = S[e];
    P[rg * 256 + 128 + oct * 8 + e] = Q[e];
  }
  __syncthreads();
  {
    float a = 0.f;
    #pragma unroll
    for (int r = 0; r < 16; ++r) a += P[r * 256 + t];
    const int slot = blockIdx.x & 63;
    if (t < 128) atomicAdd(&ws[OFF_PS2 + slot * 128 + t], a);
    else         atomicAdd(&ws[OFF_PQ2 + slot * 128 + (t - 128)], a);
  }
}

// ---------------- layer 3 (+ mean pool): out[b] = (amean@relu(bn2(h2[b])))@W3 + b3 ----------------
__global__ __launch_bounds__(256, 4) void layer3_kernel(const float* __restrict__ W3,
    const float* __restrict__ b3, const float* __restrict__ ws,
    float* __restrict__ out) {
  __shared__ float vS[4][128];
  const int w = threadIdx.x >> 6, lane = threadIdx.x & 63;
  const int item = blockIdx.x * 4 + w;
  const int f0 = lane * 2;
  const float s2a = ws[OFF_SS2 + f0],       s2b = ws[OFF_SS2 + f0 + 1];
  const float t2a = ws[OFF_SS2 + 128 + f0], t2b = ws[OFF_SS2 + 128 + f0 + 1];
  const float* am = ws + OFF_AMEAN;
  const ushortT* h2 = (const ushortT*)(ws + 29120) + UOFF_H2 + (size_t)item * 8192;
  float v0 = 0.0f, v1 = 0.0f;
  #pragma unroll 8
  for (int m = 0; m < 64; ++m) {
    uintT pk = *(const uintT*)(h2 + m * 128 + f0);
    float y0 = fmaxf(fmaf(bf2f((ushortT)(pk & 0xffffu)), s2a, t2a), 0.0f);
    float y1 = fmaxf(fmaf(bf2f((ushortT)(pk >> 16)),     s2b, t2b), 0.0f);
    float a = am[m];
    v0 = fmaf(a, y0, v0);
    v1 = fmaf(a, y1, v1);
  }
  vS[w][f0] = v0; vS[w][f0 + 1] = v1;   // same-wave producer/consumer, no barrier needed
  float o0 = b3[f0], o1 = b3[f0 + 1];
  #pragma unroll 8
  for (int kq = 0; kq < 32; ++kq) {
    float4 vk = *(const float4*)&vS[w][kq * 4];
    #pragma unroll
    for (int j = 0; j < 4; ++j) {
      float2 wr = *(const float2*)(W3 + (kq * 4 + j) * 128 + f0);
      float vj = (j == 0) ? vk.x : (j == 1) ? vk.y : (j == 2) ? vk.z : vk.w;
      o0 = fmaf(vj, wr.x, o0);
      o1 = fmaf(vj, wr.y, o1);
    }
  }
  float2 ov; ov.x = o0; ov.y = o1;
  *(float2*)(out + (size_t)item * 128 + f0) = ov;
}

extern "C" void kernel_launch(void* const* d_in, const int* in_sizes, int n_in,
                              void* d_out, int out_size, void* d_ws, size_t ws_size,
                              hipStream_t stream) {
  const float* x   = (const float*)d_in[0];
  const float* W1  = (const float*)d_in[1];
  const float* b1  = (const float*)d_in[2];
  const float* W2  = (const float*)d_in[3];
  const float* b2  = (const float*)d_in[4];
  const float* W3  = (const float*)d_in[5];
  const float* b3  = (const float*)d_in[6];
  const float* g1  = (const float*)d_in[7];
  const float* be1 = (const float*)d_in[8];
  const float* g2  = (const float*)d_in[9];
  const float* be2 = (const float*)d_in[10];
  const int*   src = (const int*)d_in[11];
  const int*   dst = (const int*)d_in[12];
  const int E = in_sizes[11];
  float* ws  = (float*)d_ws;
  float* out = (float*)d_out;

  // zero BN partial-stat slots (PS1..PQ2)
  hipMemsetAsync((void*)(ws + OFF_PS1), 0, (size_t)(29120 - OFF_PS1) * 4, stream);
  hipLaunchKernelGGL(prep_kernel,    dim3(1),    dim3(256), 0, stream, src, dst, E, W1, W2, ws);
  hipLaunchKernelGGL(wgemm1_kernel,  dim3(1024), dim3(256), 0, stream, x, ws);
  hipLaunchKernelGGL(agemm1_kernel,  dim3(1024), dim3(256), 0, stream, b1, ws);
  hipLaunchKernelGGL(stats1_kernel,  dim3(256),  dim3(256), 0, stream, ws);
  hipLaunchKernelGGL(reduce1_kernel, dim3(1),    dim3(64),  0, stream, g1, be1, ws);
  hipLaunchKernelGGL(wgemm2_kernel,  dim3(1024), dim3(256), 0, stream, ws);
  hipLaunchKernelGGL(agemm2_kernel,  dim3(1024), dim3(256), 0, stream, b2, ws);
  hipLaunchKernelGGL(stats2_kernel,  dim3(256),  dim3(256), 0, stream, ws);
  hipLaunchKernelGGL(reduce2_kernel, dim3(1),    dim3(128), 0, stream, g2, be2, ws);
  hipLaunchKernelGGL(layer3_kernel,  dim3(512),  dim3(256), 0, stream, W3, b3, ws, out);
}